// Round 2
// baseline (3260.802 us; speedup 1.0000x reference)
//
#include <hip/hip_runtime.h>
#include <hip/hip_bf16.h>
#include <math.h>

#define B_ 16
#define CIN_ 15
#define C_ 64
#define L_ 4

typedef __hip_bfloat16 bf16;

__device__ __forceinline__ float gelu_f(float x) {
    return 0.5f * x * (1.0f + erff(x * 0.70710678118654752440f));
}

#define TWO_PI_OVER_256 0.024543692606170259674f

// Per-layer repack: WPK[((j*16+ky)*64 + i)*64 + o] = {re, im}
// j<16 -> w1 (kx=j), j>=16 -> w2 (kx=240+j-16), x index = j&15.
__global__ __launch_bounds__(256) void k_repack(const float* __restrict__ w1r, const float* __restrict__ w1i,
                                                const float* __restrict__ w2r, const float* __restrict__ w2i,
                                                float2* __restrict__ WPK, int l) {
    int id = blockIdx.x * 256 + threadIdx.x;  // 2,097,152 total
    int ky = id & 15;
    int o  = (id >> 4) & 63;
    int i  = (id >> 10) & 63;
    int j  = id >> 16;  // 0..31
    int x  = j & 15;
    const float* wr = (j < 16) ? w1r : w2r;
    const float* wi = (j < 16) ? w1i : w2i;
    int src = ((l * 64 + i) * 64 + o) * 256 + x * 16 + ky;
    int dst = ((j * 16 + ky) * 64 + i) * 64 + o;
    WPK[dst] = make_float2(wr[src], wi[src]);
}

// Lift conv1x1 (15->64) + GELU. Block = (b,h) row. X stored bf16.
__global__ __launch_bounds__(256) void k_lift(const float* __restrict__ g, const float* __restrict__ lw,
                                              const float* __restrict__ lb, bf16* __restrict__ X) {
    __shared__ float gs[CIN_][256];
    __shared__ float lws[C_ * CIN_];
    __shared__ float lbs[C_];
    int b = blockIdx.x >> 8, h = blockIdx.x & 255;
    int t = threadIdx.x;
    for (int ci = 0; ci < CIN_; ci++)
        gs[ci][t] = g[((b * CIN_ + ci) * 256 + h) * 256 + t];
    for (int idx = t; idx < C_ * CIN_; idx += 256) lws[idx] = lw[idx];
    if (t < C_) lbs[t] = lb[t];
    __syncthreads();
    for (int co = 0; co < C_; co++) {
        float acc = lbs[co];
        #pragma unroll
        for (int ci = 0; ci < CIN_; ci++) acc += gs[ci][t] * lws[co * CIN_ + ci];
        X[(b * C_ + co) * 65536 + h * 256 + t] = __float2bfloat16(gelu_f(acc));
    }
}

// Forward partial rDFT over w: Y[bc][h][ky] = sum_w x * e^{-2pi i w ky/256}, ky=0..15
__global__ __launch_bounds__(256) void k_fwd_w(const bf16* __restrict__ X, float2* __restrict__ Y) {
    __shared__ float xr[16][257];
    __shared__ float tc[256], ts[256];
    int bc = blockIdx.x >> 4;
    int h0 = (blockIdx.x & 15) << 4;
    int t = threadIdx.x;
    {
        float s, c;
        sincosf((float)t * TWO_PI_OVER_256, &s, &c);
        tc[t] = c; ts[t] = s;
    }
    for (int r = 0; r < 16; r++)
        xr[r][t] = __bfloat162float(X[bc * 65536 + (h0 + r) * 256 + t]);
    __syncthreads();
    int r = t >> 4, ky = t & 15;
    float re = 0.f, im = 0.f;
    int m = 0;
    #pragma unroll 8
    for (int w = 0; w < 256; w++) {
        float v = xr[r][w];
        re += v * tc[m];
        im -= v * ts[m];
        m = (m + ky) & 255;
    }
    Y[bc * 4096 + (h0 + r) * 16 + ky] = make_float2(re, im);
}

// Forward partial DFT over h: XF[site=(j*16+ky)][b*64+c] = sum_h Y * e^{-2pi i h kxu/256}
__global__ __launch_bounds__(256) void k_fwd_h(const float2* __restrict__ Y, float2* __restrict__ XF) {
    __shared__ float2 yl[4096];
    __shared__ float tc[256], ts[256];
    int bc = blockIdx.x;
    int t = threadIdx.x;
    {
        float s, c;
        sincosf((float)t * TWO_PI_OVER_256, &s, &c);
        tc[t] = c; ts[t] = s;
    }
    for (int idx = t; idx < 4096; idx += 256) yl[idx] = Y[bc * 4096 + idx];
    __syncthreads();
    int j = t & 31, kg = t >> 5;  // kg in 0..7
    int kxu = j + ((j < 16) ? 0 : 224);
    int b = bc >> 6, c = bc & 63;
    for (int q = 0; q < 2; q++) {
        int ky = kg * 2 + q;
        float xre = 0.f, xim = 0.f;
        int m = 0;
        #pragma unroll 8
        for (int h = 0; h < 256; h++) {
            float2 yv = yl[h * 16 + ky];
            float cc = tc[m], ss = ts[m];
            xre += yv.x * cc + yv.y * ss;
            xim += yv.y * cc - yv.x * ss;
            m = (m + kxu) & 255;
        }
        XF[(j * 16 + ky) * 1024 + b * 64 + c] = make_float2(xre, xim);
    }
}

// Mode mix: YF[(b*64+o)*512+s] = sum_i XF[s][b*64+i] * WPK[s][i][o]  (complex)
__global__ __launch_bounds__(256) void k_mix(const float2* __restrict__ XF, const float2* __restrict__ WPK,
                                             float2* __restrict__ YF) {
    __shared__ float2 xs[1024];
    int s = blockIdx.x;
    int t = threadIdx.x;
    for (int idx = t; idx < 1024; idx += 256) xs[idx] = XF[s * 1024 + idx];
    __syncthreads();
    int o = t & 63, bg = t >> 6;
    float2 acc[4];
    #pragma unroll
    for (int q = 0; q < 4; q++) acc[q] = make_float2(0.f, 0.f);
    const float2* wbase = WPK + (size_t)s * 4096 + o;
    for (int i = 0; i < 64; i++) {
        float2 wv = wbase[(size_t)i * 64];
        #pragma unroll
        for (int q = 0; q < 4; q++) {
            float2 xv = xs[(bg * 4 + q) * 64 + i];
            acc[q].x += xv.x * wv.x - xv.y * wv.y;
            acc[q].y += xv.x * wv.y + xv.y * wv.x;
        }
    }
    #pragma unroll
    for (int q = 0; q < 4; q++) {
        int b = bg * 4 + q;
        YF[(b * 64 + o) * 512 + s] = acc[q];
    }
}

// Inverse DFT over kx: Z[bc][h][ky] = sum_j YF[bc][j*16+ky] * e^{+2pi i h kxu/256} (unnormalized)
__global__ __launch_bounds__(256) void k_inv_h(const float2* __restrict__ YF, float2* __restrict__ Z) {
    __shared__ float2 yl[512];
    __shared__ float tc[256], ts[256];
    int bc = blockIdx.x, t = threadIdx.x;
    {
        float s, c;
        sincosf((float)t * TWO_PI_OVER_256, &s, &c);
        tc[t] = c; ts[t] = s;
    }
    for (int idx = t; idx < 512; idx += 256) yl[idx] = YF[bc * 512 + idx];
    __syncthreads();
    float zr[16], zi[16];
    #pragma unroll
    for (int ky = 0; ky < 16; ky++) { zr[ky] = 0.f; zi[ky] = 0.f; }
    for (int j = 0; j < 32; j++) {
        int kxu = j + ((j < 16) ? 0 : 224);
        int m = (t * kxu) & 255;
        float cc = tc[m], ss = ts[m];
        #pragma unroll
        for (int ky = 0; ky < 16; ky++) {
            float2 yv = yl[j * 16 + ky];
            zr[ky] += yv.x * cc - yv.y * ss;
            zi[ky] += yv.x * ss + yv.y * cc;
        }
    }
    int base = bc * 4096 + t * 16;
    #pragma unroll
    for (int ky = 0; ky < 16; ky++) Z[base + ky] = make_float2(zr[ky], zi[ky]);
}

// Layer tail: y = irfft_w(Z)/65536 + skip conv1x1; BN(eval); x = gelu(y) + x  (in-place on X, bf16)
__global__ __launch_bounds__(256) void k_tail(bf16* __restrict__ X, const float2* __restrict__ Z,
                                              const float* __restrict__ skip_w, const float* __restrict__ skip_b,
                                              const float* __restrict__ bn_g, const float* __restrict__ bn_b,
                                              const float* __restrict__ bn_m, const float* __restrict__ bn_v,
                                              int l) {
    __shared__ bf16 xl[64 * 256];       // 32 KB
    __shared__ float2 zl[1024];         // 8 KB
    __shared__ float tc[256], ts[256];  // 2 KB
    __shared__ float scl[64], shl[64];  // 0.5 KB
    int b = blockIdx.x >> 8, h = blockIdx.x & 255;
    int t = threadIdx.x;
    {
        float s, c;
        sincosf((float)t * TWO_PI_OVER_256, &s, &c);
        tc[t] = c; ts[t] = s;
    }
    for (int c = 0; c < 64; c++)
        xl[c * 256 + t] = X[(b * 64 + c) * 65536 + h * 256 + t];
    for (int idx = t; idx < 1024; idx += 256) {
        int c = idx >> 4, ky = idx & 15;
        zl[idx] = Z[(b * 64 + c) * 4096 + h * 16 + ky];
    }
    if (t < 64) {
        float inv = 1.0f / sqrtf(bn_v[l * 64 + t] + 1e-5f);
        float sc = bn_g[l * 64 + t] * inv;
        scl[t] = sc;
        shl[t] = bn_b[l * 64 + t] - bn_m[l * 64 + t] * sc;
    }
    __syncthreads();
    // per-thread ky twiddles in registers (t fixed per thread)
    float twc[16], tws[16];
    #pragma unroll
    for (int ky = 1; ky < 16; ky++) {
        int m = (t * ky) & 255;
        twc[ky] = tc[m]; tws[ky] = ts[m];
    }
    const float* swl = skip_w + l * 4096;
    const float* sbl = skip_b + l * 64;
    for (int cg = 0; cg < 4; cg++) {
        float acc[16];
        #pragma unroll
        for (int u = 0; u < 16; u++) acc[u] = sbl[cg * 16 + u];
        for (int ci = 0; ci < 64; ci++) {
            float xv = __bfloat162float(xl[ci * 256 + t]);
            #pragma unroll
            for (int u = 0; u < 16; u++)
                acc[u] += xv * swl[(cg * 16 + u) * 64 + ci];
        }
        #pragma unroll
        for (int u = 0; u < 16; u++) {
            int co = cg * 16 + u;
            // real inverse DFT over ky (Im of ky=0 bin discarded, alpha doubling for ky>=1)
            float sp = zl[co * 16].x;
            #pragma unroll
            for (int ky = 1; ky < 16; ky++) {
                float2 zv = zl[co * 16 + ky];
                sp += 2.0f * (zv.x * twc[ky] - zv.y * tws[ky]);
            }
            float y = acc[u] + sp * (1.0f / 65536.0f);
            y = y * scl[co] + shl[co];
            float res = __bfloat162float(xl[co * 256 + t]);
            X[(b * 64 + co) * 65536 + h * 256 + t] = __float2bfloat16(gelu_f(y) + res);
        }
    }
}

// Proj conv1x1 + GELU + spatial sum (atomic accumulate into ACC[b*64+o])
__global__ __launch_bounds__(256) void k_proj(const bf16* __restrict__ X, const float* __restrict__ pw,
                                              const float* __restrict__ pb, float* __restrict__ ACC) {
    __shared__ bf16 xl[64 * 256];  // 32 KB
    __shared__ float pacc[64];
    int b = blockIdx.x >> 8, h = blockIdx.x & 255;
    int t = threadIdx.x;
    for (int c = 0; c < 64; c++)
        xl[c * 256 + t] = X[(b * 64 + c) * 65536 + h * 256 + t];
    if (t < 64) pacc[t] = 0.f;
    __syncthreads();
    int lane = t & 63;
    for (int cg = 0; cg < 4; cg++) {
        float acc[16];
        #pragma unroll
        for (int u = 0; u < 16; u++) acc[u] = pb[cg * 16 + u];
        for (int ci = 0; ci < 64; ci++) {
            float xv = __bfloat162float(xl[ci * 256 + t]);
            #pragma unroll
            for (int u = 0; u < 16; u++)
                acc[u] += xv * pw[(cg * 16 + u) * 64 + ci];
        }
        #pragma unroll
        for (int u = 0; u < 16; u++) {
            float v = gelu_f(acc[u]);
            #pragma unroll
            for (int off = 32; off > 0; off >>= 1)
                v += __shfl_down(v, off, 64);
            if (lane == 0) atomicAdd(&pacc[cg * 16 + u], v);
        }
    }
    __syncthreads();
    if (t < 64) atomicAdd(&ACC[b * 64 + t], pacc[t]);
}

// Heads: mean, concat [mean, env, d1d], 2x 3-layer MLP. One block per b.
__global__ __launch_bounds__(128) void k_head(const float* __restrict__ ACC, const float* __restrict__ env,
                                              const float* __restrict__ d1d,
                                              const float* __restrict__ dw1, const float* __restrict__ db1,
                                              const float* __restrict__ dw2, const float* __restrict__ db2,
                                              const float* __restrict__ dw3, const float* __restrict__ db3,
                                              const float* __restrict__ iw1, const float* __restrict__ ib1,
                                              const float* __restrict__ iw2, const float* __restrict__ ib2,
                                              const float* __restrict__ iw3, const float* __restrict__ ib3,
                                              float* __restrict__ out) {
    __shared__ float xc[108];
    __shared__ float h1[128];
    __shared__ float h2[64];
    int b = blockIdx.x, t = threadIdx.x;
    if (t < 64) xc[t] = ACC[b * 64 + t] * (1.0f / 65536.0f);
    else if (t < 104) xc[t] = env[b * 40 + (t - 64)];
    else if (t < 108) xc[t] = d1d[b * 4 + (t - 104)];
    __syncthreads();
    // dir head
    {
        float a = db1[t];
        for (int k = 0; k < 108; k++) a += xc[k] * dw1[t * 108 + k];
        h1[t] = gelu_f(a);
    }
    __syncthreads();
    if (t < 64) {
        float a = db2[t];
        for (int k = 0; k < 128; k++) a += h1[k] * dw2[t * 128 + k];
        h2[t] = gelu_f(a);
    }
    __syncthreads();
    if (t < 8) {
        float a = db3[t];
        for (int k = 0; k < 64; k++) a += h2[k] * dw3[t * 64 + k];
        out[b * 8 + t] = a;
    }
    __syncthreads();
    // int head
    {
        float a = ib1[t];
        for (int k = 0; k < 108; k++) a += xc[k] * iw1[t * 108 + k];
        h1[t] = gelu_f(a);
    }
    __syncthreads();
    if (t < 64) {
        float a = ib2[t];
        for (int k = 0; k < 128; k++) a += h1[k] * iw2[t * 128 + k];
        h2[t] = gelu_f(a);
    }
    __syncthreads();
    if (t < 4) {
        float a = ib3[t];
        for (int k = 0; k < 64; k++) a += h2[k] * iw3[t * 64 + k];
        out[128 + b * 4 + t] = a;
    }
}

extern "C" void kernel_launch(void* const* d_in, const int* in_sizes, int n_in,
                              void* d_out, int out_size, void* d_ws, size_t ws_size,
                              hipStream_t stream) {
    const float* grid_  = (const float*)d_in[0];
    const float* env    = (const float*)d_in[1];
    const float* d1d    = (const float*)d_in[2];
    const float* lift_w = (const float*)d_in[3];
    const float* lift_b = (const float*)d_in[4];
    const float* w1r    = (const float*)d_in[5];
    const float* w1i    = (const float*)d_in[6];
    const float* w2r    = (const float*)d_in[7];
    const float* w2i    = (const float*)d_in[8];
    const float* skip_w = (const float*)d_in[9];
    const float* skip_b = (const float*)d_in[10];
    const float* bn_g   = (const float*)d_in[11];
    const float* bn_b   = (const float*)d_in[12];
    const float* bn_m   = (const float*)d_in[13];
    const float* bn_v   = (const float*)d_in[14];
    const float* proj_w = (const float*)d_in[15];
    const float* proj_b = (const float*)d_in[16];
    const float* dw1 = (const float*)d_in[17];
    const float* db1 = (const float*)d_in[18];
    const float* dw2 = (const float*)d_in[19];
    const float* db2 = (const float*)d_in[20];
    const float* dw3 = (const float*)d_in[21];
    const float* db3 = (const float*)d_in[22];
    const float* iw1 = (const float*)d_in[23];
    const float* ib1 = (const float*)d_in[24];
    const float* iw2 = (const float*)d_in[25];
    const float* ib2 = (const float*)d_in[26];
    const float* iw3 = (const float*)d_in[27];
    const float* ib3 = (const float*)d_in[28];

    // Workspace layout (total 192,942,080 B ~= 184 MiB)
    char* ws = (char*)d_ws;
    bf16*   X   = (bf16*)(ws);                 // 134,217,728 B
    float2* S   = (float2*)(ws + 134217728);   //  33,554,432 B (Y and Z share; lifetimes disjoint)
    float2* XF  = (float2*)(ws + 167772160);   //   4,194,304 B
    float2* YF  = (float2*)(ws + 171966464);   //   4,194,304 B
    float2* WPK = (float2*)(ws + 176160768);   //  16,777,216 B (one layer at a time)
    float*  ACC = (float*)(ws + 192937984);    //       4,096 B

    hipMemsetAsync(ACC, 0, 1024 * sizeof(float), stream);
    k_lift<<<4096, 256, 0, stream>>>(grid_, lift_w, lift_b, X);
    for (int l = 0; l < L_; l++) {
        k_repack<<<8192, 256, 0, stream>>>(w1r, w1i, w2r, w2i, WPK, l);
        k_fwd_w<<<16384, 256, 0, stream>>>(X, S);
        k_fwd_h<<<1024, 256, 0, stream>>>(S, XF);
        k_mix<<<512, 256, 0, stream>>>(XF, WPK, YF);
        k_inv_h<<<1024, 256, 0, stream>>>(YF, S);
        k_tail<<<4096, 256, 0, stream>>>(X, S, skip_w, skip_b, bn_g, bn_b, bn_m, bn_v, l);
    }
    k_proj<<<4096, 256, 0, stream>>>(X, proj_w, proj_b, ACC);
    k_head<<<16, 128, 0, stream>>>(ACC, env, d1d, dw1, db1, dw2, db2, dw3, db3,
                                   iw1, ib1, iw2, ib2, iw3, ib3, (float*)d_out);
}

// Round 3
// 1781.499 us; speedup vs baseline: 1.8304x; 1.8304x over previous
//
#include <hip/hip_runtime.h>
#include <hip/hip_bf16.h>
#include <math.h>

#define B_ 16
#define CIN_ 15
#define C_ 64
#define L_ 4

typedef __attribute__((ext_vector_type(8))) short short8;
typedef __attribute__((ext_vector_type(4))) float f32x4;

__device__ __forceinline__ float gelu_f(float x) {
    return 0.5f * x * (1.0f + erff(x * 0.70710678118654752440f));
}

__device__ __forceinline__ unsigned short f2bf(float x) {
    __hip_bfloat16 h = __float2bfloat16(x);
    return *(unsigned short*)&h;
}
__device__ __forceinline__ float bf2f(unsigned short u) {
    __hip_bfloat16 h = *(__hip_bfloat16*)&u;
    return __bfloat162float(h);
}
__device__ __forceinline__ f32x4 mfma16(short8 a, short8 b, f32x4 c) {
    return __builtin_amdgcn_mfma_f32_16x16x32_bf16(a, b, c, 0, 0, 0);
}

#define TWO_PI_OVER_256 0.024543692606170259674f

// ---------------- one-time prep: split tables & weights into bf16 hi/lo ----------------
// Tf[col][w] (32x256): col<16 -> cos(2pi w col/256); col>=16 -> -sin(2pi w (col-16)/256)  [forward DFT]
// Ti[w][k]   (256x32): k=2ky -> cos(2pi w ky/256); k=2ky+1 -> -sin(2pi w ky/256)          [inverse ky recon]
// WH/WL[l][co][ci] = split(scl[l][co] * skip_w), PH/PL = split(proj_w)
__global__ __launch_bounds__(256) void k_prep(const float* __restrict__ skip_w,
                                              const float* __restrict__ bn_g, const float* __restrict__ bn_v,
                                              const float* __restrict__ proj_w,
                                              unsigned short* __restrict__ TfH, unsigned short* __restrict__ TfL,
                                              unsigned short* __restrict__ TiH, unsigned short* __restrict__ TiL,
                                              unsigned short* __restrict__ WH, unsigned short* __restrict__ WL,
                                              unsigned short* __restrict__ PH, unsigned short* __restrict__ PL) {
    int id = blockIdx.x * 256 + threadIdx.x;
    if (id < 8192) {
        int col = id >> 8, w = id & 255;
        int kk = (col < 16) ? col : (col - 16);
        float s, c;
        sincosf(TWO_PI_OVER_256 * (float)((w * kk) & 255), &s, &c);
        float v = (col < 16) ? c : -s;
        unsigned short hi = f2bf(v);
        TfH[id] = hi; TfL[id] = f2bf(v - bf2f(hi));
    } else if (id < 16384) {
        int idx = id - 8192;
        int w = idx >> 5, k = idx & 31, ky = k >> 1;
        float s, c;
        sincosf(TWO_PI_OVER_256 * (float)((w * ky) & 255), &s, &c);
        float v = (k & 1) ? -s : c;
        unsigned short hi = f2bf(v);
        TiH[idx] = hi; TiL[idx] = f2bf(v - bf2f(hi));
    } else if (id < 32768) {
        int idx = id - 16384;
        int lco = idx >> 6;  // l*64+co
        float scl = bn_g[lco] * rsqrtf(bn_v[lco] + 1e-5f);
        float v = scl * skip_w[idx];
        unsigned short hi = f2bf(v);
        WH[idx] = hi; WL[idx] = f2bf(v - bf2f(hi));
    } else if (id < 36864) {
        int idx = id - 32768;
        float v = proj_w[idx];
        unsigned short hi = f2bf(v);
        PH[idx] = hi; PL[idx] = f2bf(v - bf2f(hi));
    }
}

// ---------------- lift conv1x1 (15->64) + GELU + fused forward w-DFT ----------------
__global__ __launch_bounds__(256) void k_lift(const float* __restrict__ g, const float* __restrict__ lw,
                                              const float* __restrict__ lb, unsigned short* __restrict__ X,
                                              const unsigned short* __restrict__ TfH, const unsigned short* __restrict__ TfL,
                                              float2* __restrict__ Y) {
    __shared__ float gs[CIN_][256];
    __shared__ float lws[C_ * CIN_];
    __shared__ float lbs[C_];
    __shared__ unsigned short xl[64 * 264];
    int b = blockIdx.x >> 8, h = blockIdx.x & 255;
    int t = threadIdx.x;
    for (int ci = 0; ci < CIN_; ci++)
        gs[ci][t] = g[((b * CIN_ + ci) * 256 + h) * 256 + t];
    for (int idx = t; idx < C_ * CIN_; idx += 256) lws[idx] = lw[idx];
    if (t < C_) lbs[t] = lb[t];
    __syncthreads();
    for (int co = 0; co < C_; co++) {
        float acc = lbs[co];
        #pragma unroll
        for (int ci = 0; ci < CIN_; ci++) acc += gs[ci][t] * lws[co * CIN_ + ci];
        xl[co * 264 + t] = f2bf(gelu_f(acc));
    }
    __syncthreads();
    // forward DFT: Y[c][ky] = sum_w X[c][w] * Tf  (MFMA, A=xl exact bf16, B=Tf hi+lo)
    {
        int wv = t >> 6, ln = t & 63;
        int lx = ln & 15, q = ln >> 4;
        f32x4 fa0 = {0.f, 0.f, 0.f, 0.f}, fa1 = {0.f, 0.f, 0.f, 0.f};
        for (int ks = 0; ks < 8; ks++) {
            int k0 = ks * 32;
            short8 a = *(const short8*)(&xl[(wv * 16 + lx) * 264 + k0 + q * 8]);
            short8 bh0 = *(const short8*)(TfH + (0 * 16 + lx) * 256 + k0 + q * 8);
            short8 bl0 = *(const short8*)(TfL + (0 * 16 + lx) * 256 + k0 + q * 8);
            short8 bh1 = *(const short8*)(TfH + (1 * 16 + lx) * 256 + k0 + q * 8);
            short8 bl1 = *(const short8*)(TfL + (1 * 16 + lx) * 256 + k0 + q * 8);
            fa0 = mfma16(a, bh0, fa0); fa0 = mfma16(a, bl0, fa0);
            fa1 = mfma16(a, bh1, fa1); fa1 = mfma16(a, bl1, fa1);
        }
        #pragma unroll
        for (int r = 0; r < 4; r++) {
            int c = wv * 16 + q * 4 + r;
            Y[(b * 64 + c) * 4096 + h * 16 + lx] = make_float2(fa0[r], fa1[r]);
        }
    }
    // coalesced write of X
    for (int c = 0; c < 64; c++)
        X[(b * 64 + c) * 65536 + h * 256 + t] = xl[c * 264 + t];
}

// ---------------- forward partial DFT over h (unchanged) ----------------
__global__ __launch_bounds__(256) void k_fwd_h(const float2* __restrict__ Y, float2* __restrict__ XF) {
    __shared__ float2 yl[4096];
    __shared__ float tc[256], ts[256];
    int bc = blockIdx.x;
    int t = threadIdx.x;
    {
        float s, c;
        sincosf((float)t * TWO_PI_OVER_256, &s, &c);
        tc[t] = c; ts[t] = s;
    }
    for (int idx = t; idx < 4096; idx += 256) yl[idx] = Y[bc * 4096 + idx];
    __syncthreads();
    int j = t & 31, kg = t >> 5;
    int kxu = j + ((j < 16) ? 0 : 224);
    int b = bc >> 6, c = bc & 63;
    for (int q = 0; q < 2; q++) {
        int ky = kg * 2 + q;
        float xre = 0.f, xim = 0.f;
        int m = 0;
        #pragma unroll 8
        for (int h = 0; h < 256; h++) {
            float2 yv = yl[h * 16 + ky];
            float cc = tc[m], ss = ts[m];
            xre += yv.x * cc + yv.y * ss;
            xim += yv.y * cc - yv.x * ss;
            m = (m + kxu) & 255;
        }
        XF[(j * 16 + ky) * 1024 + b * 64 + c] = make_float2(xre, xim);
    }
}

// ---------------- per-layer spectral weight repack (unchanged) ----------------
__global__ __launch_bounds__(256) void k_repack(const float* __restrict__ w1r, const float* __restrict__ w1i,
                                                const float* __restrict__ w2r, const float* __restrict__ w2i,
                                                float2* __restrict__ WPK, int l) {
    int id = blockIdx.x * 256 + threadIdx.x;
    int ky = id & 15;
    int o  = (id >> 4) & 63;
    int i  = (id >> 10) & 63;
    int j  = id >> 16;
    int x  = j & 15;
    const float* wr = (j < 16) ? w1r : w2r;
    const float* wi = (j < 16) ? w1i : w2i;
    int src = ((l * 64 + i) * 64 + o) * 256 + x * 16 + ky;
    int dst = ((j * 16 + ky) * 64 + i) * 64 + o;
    WPK[dst] = make_float2(wr[src], wi[src]);
}

// ---------------- mode mix (unchanged) ----------------
__global__ __launch_bounds__(256) void k_mix(const float2* __restrict__ XF, const float2* __restrict__ WPK,
                                             float2* __restrict__ YF) {
    __shared__ float2 xs[1024];
    int s = blockIdx.x;
    int t = threadIdx.x;
    for (int idx = t; idx < 1024; idx += 256) xs[idx] = XF[s * 1024 + idx];
    __syncthreads();
    int o = t & 63, bg = t >> 6;
    float2 acc[4];
    #pragma unroll
    for (int q = 0; q < 4; q++) acc[q] = make_float2(0.f, 0.f);
    const float2* wbase = WPK + (size_t)s * 4096 + o;
    for (int i = 0; i < 64; i++) {
        float2 wv = wbase[(size_t)i * 64];
        #pragma unroll
        for (int q = 0; q < 4; q++) {
            float2 xv = xs[(bg * 4 + q) * 64 + i];
            acc[q].x += xv.x * wv.x - xv.y * wv.y;
            acc[q].y += xv.x * wv.y + xv.y * wv.x;
        }
    }
    #pragma unroll
    for (int q = 0; q < 4; q++) {
        int b = bg * 4 + q;
        YF[(b * 64 + o) * 512 + s] = acc[q];
    }
}

// ---------------- inverse DFT over kx (unchanged) ----------------
__global__ __launch_bounds__(256) void k_inv_h(const float2* __restrict__ YF, float2* __restrict__ Z) {
    __shared__ float2 yl[512];
    __shared__ float tc[256], ts[256];
    int bc = blockIdx.x, t = threadIdx.x;
    {
        float s, c;
        sincosf((float)t * TWO_PI_OVER_256, &s, &c);
        tc[t] = c; ts[t] = s;
    }
    for (int idx = t; idx < 512; idx += 256) yl[idx] = YF[bc * 512 + idx];
    __syncthreads();
    float zr[16], zi[16];
    #pragma unroll
    for (int ky = 0; ky < 16; ky++) { zr[ky] = 0.f; zi[ky] = 0.f; }
    for (int j = 0; j < 32; j++) {
        int kxu = j + ((j < 16) ? 0 : 224);
        int m = (t * kxu) & 255;
        float cc = tc[m], ss = ts[m];
        #pragma unroll
        for (int ky = 0; ky < 16; ky++) {
            float2 yv = yl[j * 16 + ky];
            zr[ky] += yv.x * cc - yv.y * ss;
            zi[ky] += yv.x * ss + yv.y * cc;
        }
    }
    int base = bc * 4096 + t * 16;
    #pragma unroll
    for (int ky = 0; ky < 16; ky++) Z[base + ky] = make_float2(zr[ky], zi[ky]);
}

// ---------------- layer tail: MFMA skip conv + MFMA spectral recon + BN + GELU + residual
//                  + fused forward w-DFT for next layer ----------------
__global__ __launch_bounds__(256) void k_tail(unsigned short* __restrict__ X, const float2* __restrict__ Z,
                                              const unsigned short* __restrict__ WH, const unsigned short* __restrict__ WL,
                                              const float* __restrict__ sbl, const float* __restrict__ bng,
                                              const float* __restrict__ bnb, const float* __restrict__ bnm,
                                              const float* __restrict__ bnv,
                                              const unsigned short* __restrict__ TiH, const unsigned short* __restrict__ TiL,
                                              const unsigned short* __restrict__ TfH, const unsigned short* __restrict__ TfL,
                                              float2* __restrict__ Y, int do_fwd) {
    __shared__ unsigned short xl[64 * 264];     // 33,792 B : X tile (old, then new in-place)
    __shared__ unsigned short AzH[64 * 40];     //  5,120 B : z-matrix hi (row pad 40 for banks)
    __shared__ unsigned short AzL[64 * 40];     //  5,120 B : z-matrix lo
    __shared__ float cbs[64];
    int b = blockIdx.x >> 8, h = blockIdx.x & 255;
    int t = threadIdx.x;
    // stage old X tile
    for (int c = 0; c < 64; c++)
        xl[c * 264 + t] = X[(b * 64 + c) * 65536 + h * 256 + t];
    // stage Az = scl * alpha/65536 * (zr, zi), split hi/lo
    for (int r = 0; r < 4; r++) {
        int idx = r * 256 + t;
        int co = idx >> 4, ky = idx & 15;
        float2 z = Z[(b * 64 + co) * 4096 + h * 16 + ky];
        float scl = bng[co] * rsqrtf(bnv[co] + 1e-5f);
        float f = scl * ((ky == 0) ? 1.0f : 2.0f) * (1.0f / 65536.0f);
        float ar = z.x * f, ai = z.y * f;
        unsigned short hr = f2bf(ar), hi_ = f2bf(ai);
        AzH[co * 40 + 2 * ky]     = hr;  AzL[co * 40 + 2 * ky]     = f2bf(ar - bf2f(hr));
        AzH[co * 40 + 2 * ky + 1] = hi_; AzL[co * 40 + 2 * ky + 1] = f2bf(ai - bf2f(hi_));
    }
    if (t < 64) {
        float scl = bng[t] * rsqrtf(bnv[t] + 1e-5f);
        cbs[t] = scl * (sbl[t] - bnm[t]) + bnb[t];
    }
    __syncthreads();

    int wv = t >> 6, ln = t & 63;
    int lx = ln & 15, q = ln >> 4;
    f32x4 acc[4][4];
    #pragma unroll
    for (int mt = 0; mt < 4; mt++)
        #pragma unroll
        for (int nt = 0; nt < 4; nt++)
            acc[mt][nt] = (f32x4){0.f, 0.f, 0.f, 0.f};

    // skip conv: D[co][w] += scl*W @ Xold   (A = W hi/lo from global, B = xl bf16 exact)
    for (int ks = 0; ks < 2; ks++) {
        int k0 = ks * 32;
        short8 bfr[4];
        #pragma unroll
        for (int nt = 0; nt < 4; nt++) {
            int w = wv * 64 + nt * 16 + lx;
            #pragma unroll
            for (int j = 0; j < 8; j++)
                bfr[nt][j] = (short)xl[(k0 + q * 8 + j) * 264 + w];
        }
        #pragma unroll
        for (int mt = 0; mt < 4; mt++) {
            short8 ah = *(const short8*)(WH + (mt * 16 + lx) * 64 + k0 + q * 8);
            short8 al = *(const short8*)(WL + (mt * 16 + lx) * 64 + k0 + q * 8);
            #pragma unroll
            for (int nt = 0; nt < 4; nt++) {
                acc[mt][nt] = mfma16(ah, bfr[nt], acc[mt][nt]);
                acc[mt][nt] = mfma16(al, bfr[nt], acc[mt][nt]);
            }
        }
    }
    // spectral recon: D[co][w] += Az @ Ti   (K=32; 3-term hi/lo cross product)
    {
        short8 bh[4], bl[4];
        #pragma unroll
        for (int nt = 0; nt < 4; nt++) {
            int w = wv * 64 + nt * 16 + lx;
            bh[nt] = *(const short8*)(TiH + w * 32 + q * 8);
            bl[nt] = *(const short8*)(TiL + w * 32 + q * 8);
        }
        #pragma unroll
        for (int mt = 0; mt < 4; mt++) {
            short8 ah = *(const short8*)(&AzH[(mt * 16 + lx) * 40 + q * 8]);
            short8 al = *(const short8*)(&AzL[(mt * 16 + lx) * 40 + q * 8]);
            #pragma unroll
            for (int nt = 0; nt < 4; nt++) {
                acc[mt][nt] = mfma16(ah, bh[nt], acc[mt][nt]);
                acc[mt][nt] = mfma16(ah, bl[nt], acc[mt][nt]);
                acc[mt][nt] = mfma16(al, bh[nt], acc[mt][nt]);
            }
        }
    }
    // epilogue: y = D + cb; xnew = gelu(y) + xold  (in-place; waves own disjoint w-columns)
    #pragma unroll
    for (int nt = 0; nt < 4; nt++) {
        int w = wv * 64 + nt * 16 + lx;
        #pragma unroll
        for (int mt = 0; mt < 4; mt++) {
            #pragma unroll
            for (int r = 0; r < 4; r++) {
                int co = mt * 16 + q * 4 + r;
                float y = acc[mt][nt][r] + cbs[co];
                float v = gelu_f(y) + bf2f(xl[co * 264 + w]);
                xl[co * 264 + w] = f2bf(v);
            }
        }
    }
    __syncthreads();
    // fused forward w-DFT for next layer (writes Y; Y aliases Z at this block's own slots - safe)
    if (do_fwd) {
        f32x4 fa0 = {0.f, 0.f, 0.f, 0.f}, fa1 = {0.f, 0.f, 0.f, 0.f};
        for (int ks = 0; ks < 8; ks++) {
            int k0 = ks * 32;
            short8 a = *(const short8*)(&xl[(wv * 16 + lx) * 264 + k0 + q * 8]);
            short8 bh0 = *(const short8*)(TfH + lx * 256 + k0 + q * 8);
            short8 bl0 = *(const short8*)(TfL + lx * 256 + k0 + q * 8);
            short8 bh1 = *(const short8*)(TfH + (16 + lx) * 256 + k0 + q * 8);
            short8 bl1 = *(const short8*)(TfL + (16 + lx) * 256 + k0 + q * 8);
            fa0 = mfma16(a, bh0, fa0); fa0 = mfma16(a, bl0, fa0);
            fa1 = mfma16(a, bh1, fa1); fa1 = mfma16(a, bl1, fa1);
        }
        #pragma unroll
        for (int r = 0; r < 4; r++) {
            int c = wv * 16 + q * 4 + r;
            Y[(b * 64 + c) * 4096 + h * 16 + lx] = make_float2(fa0[r], fa1[r]);
        }
    }
    // coalesced write-back of new X
    for (int c = 0; c < 64; c++)
        X[(b * 64 + c) * 65536 + h * 256 + t] = xl[c * 264 + t];
}

// ---------------- proj conv1x1 (MFMA) + GELU + spatial sum ----------------
__global__ __launch_bounds__(256) void k_proj(const unsigned short* __restrict__ X,
                                              const unsigned short* __restrict__ PH, const unsigned short* __restrict__ PL,
                                              const float* __restrict__ pb, float* __restrict__ ACC) {
    __shared__ unsigned short xl[64 * 264];
    __shared__ float pacc[64];
    __shared__ float pbs[64];
    int b = blockIdx.x >> 8, h = blockIdx.x & 255;
    int t = threadIdx.x;
    for (int c = 0; c < 64; c++)
        xl[c * 264 + t] = X[(b * 64 + c) * 65536 + h * 256 + t];
    if (t < 64) { pacc[t] = 0.f; pbs[t] = pb[t]; }
    __syncthreads();
    int wv = t >> 6, ln = t & 63;
    int lx = ln & 15, q = ln >> 4;
    f32x4 acc[4][4];
    #pragma unroll
    for (int mt = 0; mt < 4; mt++)
        #pragma unroll
        for (int nt = 0; nt < 4; nt++)
            acc[mt][nt] = (f32x4){0.f, 0.f, 0.f, 0.f};
    for (int ks = 0; ks < 2; ks++) {
        int k0 = ks * 32;
        short8 bfr[4];
        #pragma unroll
        for (int nt = 0; nt < 4; nt++) {
            int w = wv * 64 + nt * 16 + lx;
            #pragma unroll
            for (int j = 0; j < 8; j++)
                bfr[nt][j] = (short)xl[(k0 + q * 8 + j) * 264 + w];
        }
        #pragma unroll
        for (int mt = 0; mt < 4; mt++) {
            short8 ah = *(const short8*)(PH + (mt * 16 + lx) * 64 + k0 + q * 8);
            short8 al = *(const short8*)(PL + (mt * 16 + lx) * 64 + k0 + q * 8);
            #pragma unroll
            for (int nt = 0; nt < 4; nt++) {
                acc[mt][nt] = mfma16(ah, bfr[nt], acc[mt][nt]);
                acc[mt][nt] = mfma16(al, bfr[nt], acc[mt][nt]);
            }
        }
    }
    #pragma unroll
    for (int mt = 0; mt < 4; mt++) {
        #pragma unroll
        for (int r = 0; r < 4; r++) {
            int co = mt * 16 + q * 4 + r;
            float s = 0.f;
            #pragma unroll
            for (int nt = 0; nt < 4; nt++)
                s += gelu_f(acc[mt][nt][r] + pbs[co]);
            s += __shfl_xor(s, 1, 64);
            s += __shfl_xor(s, 2, 64);
            s += __shfl_xor(s, 4, 64);
            s += __shfl_xor(s, 8, 64);
            if (lx == 0) atomicAdd(&pacc[co], s);
        }
    }
    __syncthreads();
    if (t < 64) atomicAdd(&ACC[b * 64 + t], pacc[t]);
}

// ---------------- heads (unchanged) ----------------
__global__ __launch_bounds__(128) void k_head(const float* __restrict__ ACC, const float* __restrict__ env,
                                              const float* __restrict__ d1d,
                                              const float* __restrict__ dw1, const float* __restrict__ db1,
                                              const float* __restrict__ dw2, const float* __restrict__ db2,
                                              const float* __restrict__ dw3, const float* __restrict__ db3,
                                              const float* __restrict__ iw1, const float* __restrict__ ib1,
                                              const float* __restrict__ iw2, const float* __restrict__ ib2,
                                              const float* __restrict__ iw3, const float* __restrict__ ib3,
                                              float* __restrict__ out) {
    __shared__ float xc[108];
    __shared__ float h1[128];
    __shared__ float h2[64];
    int b = blockIdx.x, t = threadIdx.x;
    if (t < 64) xc[t] = ACC[b * 64 + t] * (1.0f / 65536.0f);
    else if (t < 104) xc[t] = env[b * 40 + (t - 64)];
    else if (t < 108) xc[t] = d1d[b * 4 + (t - 104)];
    __syncthreads();
    {
        float a = db1[t];
        for (int k = 0; k < 108; k++) a += xc[k] * dw1[t * 108 + k];
        h1[t] = gelu_f(a);
    }
    __syncthreads();
    if (t < 64) {
        float a = db2[t];
        for (int k = 0; k < 128; k++) a += h1[k] * dw2[t * 128 + k];
        h2[t] = gelu_f(a);
    }
    __syncthreads();
    if (t < 8) {
        float a = db3[t];
        for (int k = 0; k < 64; k++) a += h2[k] * dw3[t * 64 + k];
        out[b * 8 + t] = a;
    }
    __syncthreads();
    {
        float a = ib1[t];
        for (int k = 0; k < 108; k++) a += xc[k] * iw1[t * 108 + k];
        h1[t] = gelu_f(a);
    }
    __syncthreads();
    if (t < 64) {
        float a = ib2[t];
        for (int k = 0; k < 128; k++) a += h1[k] * iw2[t * 128 + k];
        h2[t] = gelu_f(a);
    }
    __syncthreads();
    if (t < 4) {
        float a = ib3[t];
        for (int k = 0; k < 64; k++) a += h2[k] * iw3[t * 64 + k];
        out[128 + b * 4 + t] = a;
    }
}

extern "C" void kernel_launch(void* const* d_in, const int* in_sizes, int n_in,
                              void* d_out, int out_size, void* d_ws, size_t ws_size,
                              hipStream_t stream) {
    const float* grid_  = (const float*)d_in[0];
    const float* env    = (const float*)d_in[1];
    const float* d1d    = (const float*)d_in[2];
    const float* lift_w = (const float*)d_in[3];
    const float* lift_b = (const float*)d_in[4];
    const float* w1r    = (const float*)d_in[5];
    const float* w1i    = (const float*)d_in[6];
    const float* w2r    = (const float*)d_in[7];
    const float* w2i    = (const float*)d_in[8];
    const float* skip_w = (const float*)d_in[9];
    const float* skip_b = (const float*)d_in[10];
    const float* bn_g   = (const float*)d_in[11];
    const float* bn_b   = (const float*)d_in[12];
    const float* bn_m   = (const float*)d_in[13];
    const float* bn_v   = (const float*)d_in[14];
    const float* proj_w = (const float*)d_in[15];
    const float* proj_b = (const float*)d_in[16];
    const float* dw1 = (const float*)d_in[17];
    const float* db1 = (const float*)d_in[18];
    const float* dw2 = (const float*)d_in[19];
    const float* db2 = (const float*)d_in[20];
    const float* dw3 = (const float*)d_in[21];
    const float* db3 = (const float*)d_in[22];
    const float* iw1 = (const float*)d_in[23];
    const float* ib1 = (const float*)d_in[24];
    const float* iw2 = (const float*)d_in[25];
    const float* ib2 = (const float*)d_in[26];
    const float* iw3 = (const float*)d_in[27];
    const float* ib3 = (const float*)d_in[28];

    // Workspace layout (total ~193.1 MB)
    char* ws = (char*)d_ws;
    unsigned short* X   = (unsigned short*)(ws);               // 134,217,728
    float2* S   = (float2*)(ws + 134217728);                   //  33,554,432 (Y and Z alias)
    float2* XF  = (float2*)(ws + 167772160);                   //   4,194,304
    float2* YF  = (float2*)(ws + 171966464);                   //   4,194,304
    float2* WPK = (float2*)(ws + 176160768);                   //  16,777,216
    float*  ACC = (float*)(ws + 192937984);                    //       4,096
    unsigned short* TfH = (unsigned short*)(ws + 192942080);   //      16,384
    unsigned short* TfL = (unsigned short*)(ws + 192958464);   //      16,384
    unsigned short* TiH = (unsigned short*)(ws + 192974848);   //      16,384
    unsigned short* TiL = (unsigned short*)(ws + 192991232);   //      16,384
    unsigned short* WH  = (unsigned short*)(ws + 193007616);   //      32,768
    unsigned short* WL  = (unsigned short*)(ws + 193040384);   //      32,768
    unsigned short* PH  = (unsigned short*)(ws + 193073152);   //       8,192
    unsigned short* PL  = (unsigned short*)(ws + 193081344);   //       8,192

    hipMemsetAsync(ACC, 0, 1024 * sizeof(float), stream);
    k_prep<<<144, 256, 0, stream>>>(skip_w, bn_g, bn_v, proj_w, TfH, TfL, TiH, TiL, WH, WL, PH, PL);
    k_lift<<<4096, 256, 0, stream>>>(grid_, lift_w, lift_b, X, TfH, TfL, S);
    for (int l = 0; l < L_; l++) {
        k_repack<<<8192, 256, 0, stream>>>(w1r, w1i, w2r, w2i, WPK, l);
        k_fwd_h<<<1024, 256, 0, stream>>>(S, XF);
        k_mix<<<512, 256, 0, stream>>>(XF, WPK, YF);
        k_inv_h<<<1024, 256, 0, stream>>>(YF, S);
        k_tail<<<4096, 256, 0, stream>>>(X, S, WH + l * 4096, WL + l * 4096,
                                         skip_b + l * 64, bn_g + l * 64, bn_b + l * 64,
                                         bn_m + l * 64, bn_v + l * 64,
                                         TiH, TiL, TfH, TfL, S, (l < 3) ? 1 : 0);
    }
    k_proj<<<4096, 256, 0, stream>>>(X, PH, PL, proj_b, ACC);
    k_head<<<16, 128, 0, stream>>>(ACC, env, d1d, dw1, db1, dw2, db2, dw3, db3,
                                   iw1, ib1, iw2, ib2, iw3, ib3, (float*)d_out);
}

// Round 4
// 1474.756 us; speedup vs baseline: 2.2111x; 1.2080x over previous
//
#include <hip/hip_runtime.h>
#include <hip/hip_bf16.h>
#include <math.h>

#define B_ 16
#define CIN_ 15
#define C_ 64
#define L_ 4

typedef __attribute__((ext_vector_type(8))) short short8;
typedef __attribute__((ext_vector_type(4))) float f32x4;

__device__ __forceinline__ float gelu_f(float x) {
    return 0.5f * x * (1.0f + erff(x * 0.70710678118654752440f));
}

__device__ __forceinline__ unsigned short f2bf(float x) {
    __hip_bfloat16 h = __float2bfloat16(x);
    return *(unsigned short*)&h;
}
__device__ __forceinline__ float bf2f(unsigned short u) {
    __hip_bfloat16 h = *(__hip_bfloat16*)&u;
    return __bfloat162float(h);
}
__device__ __forceinline__ f32x4 mfma16(short8 a, short8 b, f32x4 c) {
    return __builtin_amdgcn_mfma_f32_16x16x32_bf16(a, b, c, 0, 0, 0);
}

#define TWO_PI_OVER_256 0.024543692606170259674f

// ---------------- one-time prep: split tables & weights into bf16 hi/lo ----------------
__global__ __launch_bounds__(256) void k_prep(const float* __restrict__ skip_w,
                                              const float* __restrict__ bn_g, const float* __restrict__ bn_v,
                                              const float* __restrict__ proj_w,
                                              unsigned short* __restrict__ TfH, unsigned short* __restrict__ TfL,
                                              unsigned short* __restrict__ TiH, unsigned short* __restrict__ TiL,
                                              unsigned short* __restrict__ WH, unsigned short* __restrict__ WL,
                                              unsigned short* __restrict__ PH, unsigned short* __restrict__ PL) {
    int id = blockIdx.x * 256 + threadIdx.x;
    if (id < 8192) {
        int col = id >> 8, w = id & 255;
        int kk = (col < 16) ? col : (col - 16);
        float s, c;
        sincosf(TWO_PI_OVER_256 * (float)((w * kk) & 255), &s, &c);
        float v = (col < 16) ? c : -s;
        unsigned short hi = f2bf(v);
        TfH[id] = hi; TfL[id] = f2bf(v - bf2f(hi));
    } else if (id < 16384) {
        int idx = id - 8192;
        int w = idx >> 5, k = idx & 31, ky = k >> 1;
        float s, c;
        sincosf(TWO_PI_OVER_256 * (float)((w * ky) & 255), &s, &c);
        float v = (k & 1) ? -s : c;
        unsigned short hi = f2bf(v);
        TiH[idx] = hi; TiL[idx] = f2bf(v - bf2f(hi));
    } else if (id < 32768) {
        int idx = id - 16384;
        int lco = idx >> 6;
        float scl = bn_g[lco] * rsqrtf(bn_v[lco] + 1e-5f);
        float v = scl * skip_w[idx];
        unsigned short hi = f2bf(v);
        WH[idx] = hi; WL[idx] = f2bf(v - bf2f(hi));
    } else if (id < 36864) {
        int idx = id - 32768;
        float v = proj_w[idx];
        unsigned short hi = f2bf(v);
        PH[idx] = hi; PL[idx] = f2bf(v - bf2f(hi));
    }
}

// ---------------- lift conv1x1 (15->64) + GELU + fused forward w-DFT ----------------
__global__ __launch_bounds__(256) void k_lift(const float* __restrict__ g, const float* __restrict__ lw,
                                              const float* __restrict__ lb, unsigned short* __restrict__ X,
                                              const unsigned short* __restrict__ TfH, const unsigned short* __restrict__ TfL,
                                              float2* __restrict__ Y) {
    __shared__ float gs[CIN_][256];
    __shared__ float lws[C_ * CIN_];
    __shared__ float lbs[C_];
    __shared__ unsigned short xl[64 * 264];
    int b = blockIdx.x >> 8, h = blockIdx.x & 255;
    int t = threadIdx.x;
    for (int ci = 0; ci < CIN_; ci++)
        gs[ci][t] = g[((b * CIN_ + ci) * 256 + h) * 256 + t];
    for (int idx = t; idx < C_ * CIN_; idx += 256) lws[idx] = lw[idx];
    if (t < C_) lbs[t] = lb[t];
    __syncthreads();
    for (int co = 0; co < C_; co++) {
        float acc = lbs[co];
        #pragma unroll
        for (int ci = 0; ci < CIN_; ci++) acc += gs[ci][t] * lws[co * CIN_ + ci];
        xl[co * 264 + t] = f2bf(gelu_f(acc));
    }
    __syncthreads();
    // forward DFT: Y[c][ky] = sum_w X[c][w] * Tf
    {
        int wv = t >> 6, ln = t & 63;
        int lx = ln & 15, q = ln >> 4;
        f32x4 fa0 = {0.f, 0.f, 0.f, 0.f}, fa1 = {0.f, 0.f, 0.f, 0.f};
        for (int ks = 0; ks < 8; ks++) {
            int k0 = ks * 32;
            short8 a = *(const short8*)(&xl[(wv * 16 + lx) * 264 + k0 + q * 8]);
            short8 bh0 = *(const short8*)(TfH + lx * 256 + k0 + q * 8);
            short8 bl0 = *(const short8*)(TfL + lx * 256 + k0 + q * 8);
            short8 bh1 = *(const short8*)(TfH + (16 + lx) * 256 + k0 + q * 8);
            short8 bl1 = *(const short8*)(TfL + (16 + lx) * 256 + k0 + q * 8);
            fa0 = mfma16(a, bh0, fa0); fa0 = mfma16(a, bl0, fa0);
            fa1 = mfma16(a, bh1, fa1); fa1 = mfma16(a, bl1, fa1);
        }
        #pragma unroll
        for (int r = 0; r < 4; r++) {
            int c = wv * 16 + q * 4 + r;
            Y[(b * 64 + c) * 4096 + h * 16 + lx] = make_float2(fa0[r], fa1[r]);
        }
    }
    // vectorized coalesced write of X (16B per lane)
    unsigned short* Xg = X + (size_t)(b * 64) * 65536 + h * 256;
    #pragma unroll
    for (int r = 0; r < 8; r++) {
        int idx = r * 256 + t;
        int c = idx >> 5, w8 = idx & 31;
        *(short8*)(Xg + c * 65536 + w8 * 8) = *(const short8*)(&xl[c * 264 + w8 * 8]);
    }
}

// ---------------- forward partial DFT over h (unchanged) ----------------
__global__ __launch_bounds__(256) void k_fwd_h(const float2* __restrict__ Y, float2* __restrict__ XF) {
    __shared__ float2 yl[4096];
    __shared__ float tc[256], ts[256];
    int bc = blockIdx.x;
    int t = threadIdx.x;
    {
        float s, c;
        sincosf((float)t * TWO_PI_OVER_256, &s, &c);
        tc[t] = c; ts[t] = s;
    }
    for (int idx = t; idx < 4096; idx += 256) yl[idx] = Y[bc * 4096 + idx];
    __syncthreads();
    int j = t & 31, kg = t >> 5;
    int kxu = j + ((j < 16) ? 0 : 224);
    int b = bc >> 6, c = bc & 63;
    for (int q = 0; q < 2; q++) {
        int ky = kg * 2 + q;
        float xre = 0.f, xim = 0.f;
        int m = 0;
        #pragma unroll 8
        for (int h = 0; h < 256; h++) {
            float2 yv = yl[h * 16 + ky];
            float cc = tc[m], ss = ts[m];
            xre += yv.x * cc + yv.y * ss;
            xim += yv.y * cc - yv.x * ss;
            m = (m + kxu) & 255;
        }
        XF[(j * 16 + ky) * 1024 + b * 64 + c] = make_float2(xre, xim);
    }
}

// ---------------- per-layer spectral weight repack (unchanged) ----------------
__global__ __launch_bounds__(256) void k_repack(const float* __restrict__ w1r, const float* __restrict__ w1i,
                                                const float* __restrict__ w2r, const float* __restrict__ w2i,
                                                float2* __restrict__ WPK, int l) {
    int id = blockIdx.x * 256 + threadIdx.x;
    int ky = id & 15;
    int o  = (id >> 4) & 63;
    int i  = (id >> 10) & 63;
    int j  = id >> 16;
    int x  = j & 15;
    const float* wr = (j < 16) ? w1r : w2r;
    const float* wi = (j < 16) ? w1i : w2i;
    int src = ((l * 64 + i) * 64 + o) * 256 + x * 16 + ky;
    int dst = ((j * 16 + ky) * 64 + i) * 64 + o;
    WPK[dst] = make_float2(wr[src], wi[src]);
}

// ---------------- mode mix (unchanged) ----------------
__global__ __launch_bounds__(256) void k_mix(const float2* __restrict__ XF, const float2* __restrict__ WPK,
                                             float2* __restrict__ YF) {
    __shared__ float2 xs[1024];
    int s = blockIdx.x;
    int t = threadIdx.x;
    for (int idx = t; idx < 1024; idx += 256) xs[idx] = XF[s * 1024 + idx];
    __syncthreads();
    int o = t & 63, bg = t >> 6;
    float2 acc[4];
    #pragma unroll
    for (int q = 0; q < 4; q++) acc[q] = make_float2(0.f, 0.f);
    const float2* wbase = WPK + (size_t)s * 4096 + o;
    for (int i = 0; i < 64; i++) {
        float2 wv = wbase[(size_t)i * 64];
        #pragma unroll
        for (int q = 0; q < 4; q++) {
            float2 xv = xs[(bg * 4 + q) * 64 + i];
            acc[q].x += xv.x * wv.x - xv.y * wv.y;
            acc[q].y += xv.x * wv.y + xv.y * wv.x;
        }
    }
    #pragma unroll
    for (int q = 0; q < 4; q++) {
        int b = bg * 4 + q;
        YF[(b * 64 + o) * 512 + s] = acc[q];
    }
}

// ---------------- inverse DFT over kx (unchanged) ----------------
__global__ __launch_bounds__(256) void k_inv_h(const float2* __restrict__ YF, float2* __restrict__ Z) {
    __shared__ float2 yl[512];
    __shared__ float tc[256], ts[256];
    int bc = blockIdx.x, t = threadIdx.x;
    {
        float s, c;
        sincosf((float)t * TWO_PI_OVER_256, &s, &c);
        tc[t] = c; ts[t] = s;
    }
    for (int idx = t; idx < 512; idx += 256) yl[idx] = YF[bc * 512 + idx];
    __syncthreads();
    float zr[16], zi[16];
    #pragma unroll
    for (int ky = 0; ky < 16; ky++) { zr[ky] = 0.f; zi[ky] = 0.f; }
    for (int j = 0; j < 32; j++) {
        int kxu = j + ((j < 16) ? 0 : 224);
        int m = (t * kxu) & 255;
        float cc = tc[m], ss = ts[m];
        #pragma unroll
        for (int ky = 0; ky < 16; ky++) {
            float2 yv = yl[j * 16 + ky];
            zr[ky] += yv.x * cc - yv.y * ss;
            zi[ky] += yv.x * ss + yv.y * cc;
        }
    }
    int base = bc * 4096 + t * 16;
    #pragma unroll
    for (int ky = 0; ky < 16; ky++) Z[base + ky] = make_float2(zr[ky], zi[ky]);
}

// ---------------- layer tail: MFMA skip conv + MFMA spectral recon + BN + GELU + residual
//  mode 1 (l<3): + fused forward w-DFT for next layer, + X writeback
//  mode 2 (l=3): + fused proj conv + GELU + spatial sum (no X writeback) ----------------
__global__ __launch_bounds__(256) void k_tail(unsigned short* __restrict__ X, const float2* __restrict__ Z,
                                              const unsigned short* __restrict__ WH, const unsigned short* __restrict__ WL,
                                              const float* __restrict__ sbl, const float* __restrict__ bng,
                                              const float* __restrict__ bnb, const float* __restrict__ bnm,
                                              const float* __restrict__ bnv,
                                              const unsigned short* __restrict__ TiH, const unsigned short* __restrict__ TiL,
                                              const unsigned short* __restrict__ TfH, const unsigned short* __restrict__ TfL,
                                              float2* __restrict__ Y, int mode,
                                              const unsigned short* __restrict__ PH, const unsigned short* __restrict__ PL,
                                              const float* __restrict__ pb, float* __restrict__ ACC) {
    __shared__ unsigned short xl[64 * 264];   // 33,792 B
    __shared__ float cbs[64];
    __shared__ float pacc[64];
    __shared__ float pbs[64];
    int b = blockIdx.x >> 8, h = blockIdx.x & 255;
    int t = threadIdx.x;
    unsigned short* Xg = X + (size_t)(b * 64) * 65536 + h * 256;
    // vectorized staging: 16B per lane
    #pragma unroll
    for (int r = 0; r < 8; r++) {
        int idx = r * 256 + t;
        int c = idx >> 5, w8 = idx & 31;
        *(short8*)(&xl[c * 264 + w8 * 8]) = *(const short8*)(Xg + c * 65536 + w8 * 8);
    }
    if (t < 64) {
        float scl = bng[t] * rsqrtf(bnv[t] + 1e-5f);
        cbs[t] = scl * (sbl[t] - bnm[t]) + bnb[t];
        pacc[t] = 0.f;
        pbs[t] = pb[t];
    }
    __syncthreads();

    int wv = t >> 6, ln = t & 63;
    int lx = ln & 15, q = ln >> 4;
    f32x4 acc[4][4];
    #pragma unroll
    for (int mt = 0; mt < 4; mt++)
        #pragma unroll
        for (int nt = 0; nt < 4; nt++)
            acc[mt][nt] = (f32x4){0.f, 0.f, 0.f, 0.f};

    // ---- spectral recon: Az built in registers from contiguous 32B Z loads ----
    {
        short8 tbh[4], tbl[4];
        #pragma unroll
        for (int nt = 0; nt < 4; nt++) {
            int w = wv * 64 + nt * 16 + lx;
            tbh[nt] = *(const short8*)(TiH + w * 32 + q * 8);
            tbl[nt] = *(const short8*)(TiL + w * 32 + q * 8);
        }
        const float2* Zg = Z + (size_t)(b * 64) * 4096 + h * 16;
        #pragma unroll
        for (int mt = 0; mt < 4; mt++) {
            int co = mt * 16 + lx;
            float scl = bng[co] * rsqrtf(bnv[co] + 1e-5f);
            float f2v = scl * (2.0f / 65536.0f);
            float f0 = (q == 0) ? (scl * (1.0f / 65536.0f)) : f2v;
            const float4* zp = (const float4*)(Zg + (size_t)co * 4096 + q * 4);
            float4 z0 = zp[0], z1 = zp[1];
            float v[8];
            v[0] = z0.x * f0;  v[1] = z0.y * f0;
            v[2] = z0.z * f2v; v[3] = z0.w * f2v;
            v[4] = z1.x * f2v; v[5] = z1.y * f2v;
            v[6] = z1.z * f2v; v[7] = z1.w * f2v;
            short8 ah, al;
            #pragma unroll
            for (int j = 0; j < 8; j++) {
                unsigned short hv = f2bf(v[j]);
                ah[j] = (short)hv;
                al[j] = (short)f2bf(v[j] - bf2f(hv));
            }
            #pragma unroll
            for (int nt = 0; nt < 4; nt++) {
                acc[mt][nt] = mfma16(ah, tbh[nt], acc[mt][nt]);
                acc[mt][nt] = mfma16(ah, tbl[nt], acc[mt][nt]);
                acc[mt][nt] = mfma16(al, tbh[nt], acc[mt][nt]);
            }
        }
    }
    // ---- skip conv: D[co][w] += scl*W @ Xold ----
    for (int ks = 0; ks < 2; ks++) {
        int k0 = ks * 32;
        short8 bfr[4];
        #pragma unroll
        for (int nt = 0; nt < 4; nt++) {
            int w = wv * 64 + nt * 16 + lx;
            #pragma unroll
            for (int j = 0; j < 8; j++)
                bfr[nt][j] = (short)xl[(k0 + q * 8 + j) * 264 + w];
        }
        #pragma unroll
        for (int mt = 0; mt < 4; mt++) {
            short8 ah = *(const short8*)(WH + (mt * 16 + lx) * 64 + k0 + q * 8);
            short8 al = *(const short8*)(WL + (mt * 16 + lx) * 64 + k0 + q * 8);
            #pragma unroll
            for (int nt = 0; nt < 4; nt++) {
                acc[mt][nt] = mfma16(ah, bfr[nt], acc[mt][nt]);
                acc[mt][nt] = mfma16(al, bfr[nt], acc[mt][nt]);
            }
        }
    }
    // ---- epilogue: xnew = gelu(D + cb) + xold (in-place; waves own disjoint w-columns) ----
    #pragma unroll
    for (int nt = 0; nt < 4; nt++) {
        int w = wv * 64 + nt * 16 + lx;
        #pragma unroll
        for (int mt = 0; mt < 4; mt++) {
            #pragma unroll
            for (int r = 0; r < 4; r++) {
                int co = mt * 16 + q * 4 + r;
                float y = acc[mt][nt][r] + cbs[co];
                float v = gelu_f(y) + bf2f(xl[co * 264 + w]);
                xl[co * 264 + w] = f2bf(v);
            }
        }
    }
    __syncthreads();

    if (mode == 1) {
        // fused forward w-DFT for next layer
        f32x4 fa0 = {0.f, 0.f, 0.f, 0.f}, fa1 = {0.f, 0.f, 0.f, 0.f};
        for (int ks = 0; ks < 8; ks++) {
            int k0 = ks * 32;
            short8 a = *(const short8*)(&xl[(wv * 16 + lx) * 264 + k0 + q * 8]);
            short8 bh0 = *(const short8*)(TfH + lx * 256 + k0 + q * 8);
            short8 bl0 = *(const short8*)(TfL + lx * 256 + k0 + q * 8);
            short8 bh1 = *(const short8*)(TfH + (16 + lx) * 256 + k0 + q * 8);
            short8 bl1 = *(const short8*)(TfL + (16 + lx) * 256 + k0 + q * 8);
            fa0 = mfma16(a, bh0, fa0); fa0 = mfma16(a, bl0, fa0);
            fa1 = mfma16(a, bh1, fa1); fa1 = mfma16(a, bl1, fa1);
        }
        #pragma unroll
        for (int r = 0; r < 4; r++) {
            int c = wv * 16 + q * 4 + r;
            Y[(b * 64 + c) * 4096 + h * 16 + lx] = make_float2(fa0[r], fa1[r]);
        }
        // vectorized X writeback
        #pragma unroll
        for (int r = 0; r < 8; r++) {
            int idx = r * 256 + t;
            int c = idx >> 5, w8 = idx & 31;
            *(short8*)(Xg + c * 65536 + w8 * 8) = *(const short8*)(&xl[c * 264 + w8 * 8]);
        }
    } else {
        // fused proj conv + GELU + spatial sum (reads NEW xl)
        #pragma unroll
        for (int mt = 0; mt < 4; mt++)
            #pragma unroll
            for (int nt = 0; nt < 4; nt++)
                acc[mt][nt] = (f32x4){0.f, 0.f, 0.f, 0.f};
        for (int ks = 0; ks < 2; ks++) {
            int k0 = ks * 32;
            short8 bfr[4];
            #pragma unroll
            for (int nt = 0; nt < 4; nt++) {
                int w = wv * 64 + nt * 16 + lx;
                #pragma unroll
                for (int j = 0; j < 8; j++)
                    bfr[nt][j] = (short)xl[(k0 + q * 8 + j) * 264 + w];
            }
            #pragma unroll
            for (int mt = 0; mt < 4; mt++) {
                short8 ah = *(const short8*)(PH + (mt * 16 + lx) * 64 + k0 + q * 8);
                short8 al = *(const short8*)(PL + (mt * 16 + lx) * 64 + k0 + q * 8);
                #pragma unroll
                for (int nt = 0; nt < 4; nt++) {
                    acc[mt][nt] = mfma16(ah, bfr[nt], acc[mt][nt]);
                    acc[mt][nt] = mfma16(al, bfr[nt], acc[mt][nt]);
                }
            }
        }
        #pragma unroll
        for (int mt = 0; mt < 4; mt++) {
            #pragma unroll
            for (int r = 0; r < 4; r++) {
                int co = mt * 16 + q * 4 + r;
                float s = 0.f;
                #pragma unroll
                for (int nt = 0; nt < 4; nt++)
                    s += gelu_f(acc[mt][nt][r] + pbs[co]);
                s += __shfl_xor(s, 1, 64);
                s += __shfl_xor(s, 2, 64);
                s += __shfl_xor(s, 4, 64);
                s += __shfl_xor(s, 8, 64);
                if (lx == 0) atomicAdd(&pacc[co], s);
            }
        }
        __syncthreads();
        if (t < 64) atomicAdd(&ACC[b * 64 + t], pacc[t]);
    }
}

// ---------------- heads (unchanged) ----------------
__global__ __launch_bounds__(128) void k_head(const float* __restrict__ ACC, const float* __restrict__ env,
                                              const float* __restrict__ d1d,
                                              const float* __restrict__ dw1, const float* __restrict__ db1,
                                              const float* __restrict__ dw2, const float* __restrict__ db2,
                                              const float* __restrict__ dw3, const float* __restrict__ db3,
                                              const float* __restrict__ iw1, const float* __restrict__ ib1,
                                              const float* __restrict__ iw2, const float* __restrict__ ib2,
                                              const float* __restrict__ iw3, const float* __restrict__ ib3,
                                              float* __restrict__ out) {
    __shared__ float xc[108];
    __shared__ float h1[128];
    __shared__ float h2[64];
    int b = blockIdx.x, t = threadIdx.x;
    if (t < 64) xc[t] = ACC[b * 64 + t] * (1.0f / 65536.0f);
    else if (t < 104) xc[t] = env[b * 40 + (t - 64)];
    else if (t < 108) xc[t] = d1d[b * 4 + (t - 104)];
    __syncthreads();
    {
        float a = db1[t];
        for (int k = 0; k < 108; k++) a += xc[k] * dw1[t * 108 + k];
        h1[t] = gelu_f(a);
    }
    __syncthreads();
    if (t < 64) {
        float a = db2[t];
        for (int k = 0; k < 128; k++) a += h1[k] * dw2[t * 128 + k];
        h2[t] = gelu_f(a);
    }
    __syncthreads();
    if (t < 8) {
        float a = db3[t];
        for (int k = 0; k < 64; k++) a += h2[k] * dw3[t * 64 + k];
        out[b * 8 + t] = a;
    }
    __syncthreads();
    {
        float a = ib1[t];
        for (int k = 0; k < 108; k++) a += xc[k] * iw1[t * 108 + k];
        h1[t] = gelu_f(a);
    }
    __syncthreads();
    if (t < 64) {
        float a = ib2[t];
        for (int k = 0; k < 128; k++) a += h1[k] * iw2[t * 128 + k];
        h2[t] = gelu_f(a);
    }
    __syncthreads();
    if (t < 4) {
        float a = ib3[t];
        for (int k = 0; k < 64; k++) a += h2[k] * iw3[t * 64 + k];
        out[128 + b * 4 + t] = a;
    }
}

extern "C" void kernel_launch(void* const* d_in, const int* in_sizes, int n_in,
                              void* d_out, int out_size, void* d_ws, size_t ws_size,
                              hipStream_t stream) {
    const float* grid_  = (const float*)d_in[0];
    const float* env    = (const float*)d_in[1];
    const float* d1d    = (const float*)d_in[2];
    const float* lift_w = (const float*)d_in[3];
    const float* lift_b = (const float*)d_in[4];
    const float* w1r    = (const float*)d_in[5];
    const float* w1i    = (const float*)d_in[6];
    const float* w2r    = (const float*)d_in[7];
    const float* w2i    = (const float*)d_in[8];
    const float* skip_w = (const float*)d_in[9];
    const float* skip_b = (const float*)d_in[10];
    const float* bn_g   = (const float*)d_in[11];
    const float* bn_b   = (const float*)d_in[12];
    const float* bn_m   = (const float*)d_in[13];
    const float* bn_v   = (const float*)d_in[14];
    const float* proj_w = (const float*)d_in[15];
    const float* proj_b = (const float*)d_in[16];
    const float* dw1 = (const float*)d_in[17];
    const float* db1 = (const float*)d_in[18];
    const float* dw2 = (const float*)d_in[19];
    const float* db2 = (const float*)d_in[20];
    const float* dw3 = (const float*)d_in[21];
    const float* db3 = (const float*)d_in[22];
    const float* iw1 = (const float*)d_in[23];
    const float* ib1 = (const float*)d_in[24];
    const float* iw2 = (const float*)d_in[25];
    const float* ib2 = (const float*)d_in[26];
    const float* iw3 = (const float*)d_in[27];
    const float* ib3 = (const float*)d_in[28];

    // Workspace layout (total ~193.1 MB)
    char* ws = (char*)d_ws;
    unsigned short* X   = (unsigned short*)(ws);               // 134,217,728
    float2* S   = (float2*)(ws + 134217728);                   //  33,554,432 (Y and Z alias)
    float2* XF  = (float2*)(ws + 167772160);                   //   4,194,304
    float2* YF  = (float2*)(ws + 171966464);                   //   4,194,304
    float2* WPK = (float2*)(ws + 176160768);                   //  16,777,216
    float*  ACC = (float*)(ws + 192937984);                    //       4,096
    unsigned short* TfH = (unsigned short*)(ws + 192942080);   //      16,384
    unsigned short* TfL = (unsigned short*)(ws + 192958464);   //      16,384
    unsigned short* TiH = (unsigned short*)(ws + 192974848);   //      16,384
    unsigned short* TiL = (unsigned short*)(ws + 192991232);   //      16,384
    unsigned short* WH  = (unsigned short*)(ws + 193007616);   //      32,768
    unsigned short* WL  = (unsigned short*)(ws + 193040384);   //      32,768
    unsigned short* PH  = (unsigned short*)(ws + 193073152);   //       8,192
    unsigned short* PL  = (unsigned short*)(ws + 193081344);   //       8,192

    hipMemsetAsync(ACC, 0, 1024 * sizeof(float), stream);
    k_prep<<<144, 256, 0, stream>>>(skip_w, bn_g, bn_v, proj_w, TfH, TfL, TiH, TiL, WH, WL, PH, PL);
    k_lift<<<4096, 256, 0, stream>>>(grid_, lift_w, lift_b, X, TfH, TfL, S);
    for (int l = 0; l < L_; l++) {
        k_repack<<<8192, 256, 0, stream>>>(w1r, w1i, w2r, w2i, WPK, l);
        k_fwd_h<<<1024, 256, 0, stream>>>(S, XF);
        k_mix<<<512, 256, 0, stream>>>(XF, WPK, YF);
        k_inv_h<<<1024, 256, 0, stream>>>(YF, S);
        k_tail<<<4096, 256, 0, stream>>>(X, S, WH + l * 4096, WL + l * 4096,
                                         skip_b + l * 64, bn_g + l * 64, bn_b + l * 64,
                                         bn_m + l * 64, bn_v + l * 64,
                                         TiH, TiL, TfH, TfL, S, (l < 3) ? 1 : 2,
                                         PH, PL, proj_b, ACC);
    }
    k_head<<<16, 128, 0, stream>>>(ACC, env, d1d, dw1, db1, dw2, db2, dw3, db3,
                                   iw1, ib1, iw2, ib2, iw3, ib3, (float*)d_out);
}

// Round 5
// 1384.012 us; speedup vs baseline: 2.3561x; 1.0656x over previous
//
#include <hip/hip_runtime.h>
#include <hip/hip_bf16.h>
#include <math.h>

#define B_ 16
#define CIN_ 15
#define C_ 64
#define L_ 4

typedef __attribute__((ext_vector_type(8))) short short8;
typedef __attribute__((ext_vector_type(4))) float f32x4;

// Fast exact-GELU: erf via Abramowitz-Stegun 7.1.26 (|eps| <= 1.5e-7), branchless.
// gelu(x) = 0.5*(x + |x|*E), E = 1 - poly(t)*exp(-z^2), z=|x|/sqrt2, t=1/(1+0.3275911 z)
__device__ __forceinline__ float gelu_f(float x) {
    float z = fabsf(x) * 0.70710678118654752440f;
    float t = __builtin_amdgcn_rcpf(fmaf(0.3275911f, z, 1.0f));
    float p = t * fmaf(t, fmaf(t, fmaf(t, fmaf(t, 1.061405429f, -1.453152027f), 1.421413741f), -0.284496736f), 0.254829592f);
    float e = __expf(-z * z);
    float E = fmaf(-p, e, 1.0f);
    return 0.5f * fmaf(fabsf(x), E, x);
}

__device__ __forceinline__ unsigned short f2bf(float x) {
    __hip_bfloat16 h = __float2bfloat16(x);
    return *(unsigned short*)&h;
}
__device__ __forceinline__ float bf2f(unsigned short u) {
    __hip_bfloat16 h = *(__hip_bfloat16*)&u;
    return __bfloat162float(h);
}
__device__ __forceinline__ f32x4 mfma16(short8 a, short8 b, f32x4 c) {
    return __builtin_amdgcn_mfma_f32_16x16x32_bf16(a, b, c, 0, 0, 0);
}

#define TWO_PI_OVER_256 0.024543692606170259674f

// ---------------- one-time prep: split tables & weights into bf16 hi/lo ----------------
__global__ __launch_bounds__(256) void k_prep(const float* __restrict__ skip_w,
                                              const float* __restrict__ bn_g, const float* __restrict__ bn_v,
                                              const float* __restrict__ proj_w,
                                              unsigned short* __restrict__ TfH, unsigned short* __restrict__ TfL,
                                              unsigned short* __restrict__ TiH, unsigned short* __restrict__ TiL,
                                              unsigned short* __restrict__ WH, unsigned short* __restrict__ WL,
                                              unsigned short* __restrict__ PH, unsigned short* __restrict__ PL) {
    int id = blockIdx.x * 256 + threadIdx.x;
    if (id < 8192) {
        int col = id >> 8, w = id & 255;
        int kk = (col < 16) ? col : (col - 16);
        float s, c;
        sincosf(TWO_PI_OVER_256 * (float)((w * kk) & 255), &s, &c);
        float v = (col < 16) ? c : -s;
        unsigned short hi = f2bf(v);
        TfH[id] = hi; TfL[id] = f2bf(v - bf2f(hi));
    } else if (id < 16384) {
        int idx = id - 8192;
        int w = idx >> 5, k = idx & 31, ky = k >> 1;
        float s, c;
        sincosf(TWO_PI_OVER_256 * (float)((w * ky) & 255), &s, &c);
        float v = (k & 1) ? -s : c;
        unsigned short hi = f2bf(v);
        TiH[idx] = hi; TiL[idx] = f2bf(v - bf2f(hi));
    } else if (id < 32768) {
        int idx = id - 16384;
        int lco = idx >> 6;
        float scl = bn_g[lco] * rsqrtf(bn_v[lco] + 1e-5f);
        float v = scl * skip_w[idx];
        unsigned short hi = f2bf(v);
        WH[idx] = hi; WL[idx] = f2bf(v - bf2f(hi));
    } else if (id < 36864) {
        int idx = id - 32768;
        float v = proj_w[idx];
        unsigned short hi = f2bf(v);
        PH[idx] = hi; PL[idx] = f2bf(v - bf2f(hi));
    }
}

// ---------------- lift conv1x1 (15->64) + GELU + fused forward w-DFT ----------------
__global__ __launch_bounds__(256) void k_lift(const float* __restrict__ g, const float* __restrict__ lw,
                                              const float* __restrict__ lb, unsigned short* __restrict__ X,
                                              const unsigned short* __restrict__ TfH, const unsigned short* __restrict__ TfL,
                                              float2* __restrict__ Y) {
    __shared__ float gs[CIN_][256];
    __shared__ float lws[C_ * CIN_];
    __shared__ float lbs[C_];
    __shared__ unsigned short xl[64 * 264];
    int b = blockIdx.x >> 8, h = blockIdx.x & 255;
    int t = threadIdx.x;
    for (int ci = 0; ci < CIN_; ci++)
        gs[ci][t] = g[((b * CIN_ + ci) * 256 + h) * 256 + t];
    for (int idx = t; idx < C_ * CIN_; idx += 256) lws[idx] = lw[idx];
    if (t < C_) lbs[t] = lb[t];
    __syncthreads();
    for (int co = 0; co < C_; co++) {
        float acc = lbs[co];
        #pragma unroll
        for (int ci = 0; ci < CIN_; ci++) acc += gs[ci][t] * lws[co * CIN_ + ci];
        xl[co * 264 + t] = f2bf(gelu_f(acc));
    }
    __syncthreads();
    // forward DFT: Y[c][ky] = sum_w X[c][w] * Tf
    {
        int wv = t >> 6, ln = t & 63;
        int lx = ln & 15, q = ln >> 4;
        f32x4 fa0 = {0.f, 0.f, 0.f, 0.f}, fa1 = {0.f, 0.f, 0.f, 0.f};
        for (int ks = 0; ks < 8; ks++) {
            int k0 = ks * 32;
            short8 a = *(const short8*)(&xl[(wv * 16 + lx) * 264 + k0 + q * 8]);
            short8 bh0 = *(const short8*)(TfH + lx * 256 + k0 + q * 8);
            short8 bl0 = *(const short8*)(TfL + lx * 256 + k0 + q * 8);
            short8 bh1 = *(const short8*)(TfH + (16 + lx) * 256 + k0 + q * 8);
            short8 bl1 = *(const short8*)(TfL + (16 + lx) * 256 + k0 + q * 8);
            fa0 = mfma16(a, bh0, fa0); fa0 = mfma16(a, bl0, fa0);
            fa1 = mfma16(a, bh1, fa1); fa1 = mfma16(a, bl1, fa1);
        }
        #pragma unroll
        for (int r = 0; r < 4; r++) {
            int c = wv * 16 + q * 4 + r;
            Y[(b * 64 + c) * 4096 + h * 16 + lx] = make_float2(fa0[r], fa1[r]);
        }
    }
    // vectorized coalesced write of X (16B per lane)
    unsigned short* Xg = X + (size_t)(b * 64) * 65536 + h * 256;
    #pragma unroll
    for (int r = 0; r < 8; r++) {
        int idx = r * 256 + t;
        int c = idx >> 5, w8 = idx & 31;
        *(short8*)(Xg + c * 65536 + w8 * 8) = *(const short8*)(&xl[c * 264 + w8 * 8]);
    }
}

// ---------------- forward partial DFT over h (unchanged) ----------------
__global__ __launch_bounds__(256) void k_fwd_h(const float2* __restrict__ Y, float2* __restrict__ XF) {
    __shared__ float2 yl[4096];
    __shared__ float tc[256], ts[256];
    int bc = blockIdx.x;
    int t = threadIdx.x;
    {
        float s, c;
        sincosf((float)t * TWO_PI_OVER_256, &s, &c);
        tc[t] = c; ts[t] = s;
    }
    for (int idx = t; idx < 4096; idx += 256) yl[idx] = Y[bc * 4096 + idx];
    __syncthreads();
    int j = t & 31, kg = t >> 5;
    int kxu = j + ((j < 16) ? 0 : 224);
    int b = bc >> 6, c = bc & 63;
    for (int q = 0; q < 2; q++) {
        int ky = kg * 2 + q;
        float xre = 0.f, xim = 0.f;
        int m = 0;
        #pragma unroll 8
        for (int h = 0; h < 256; h++) {
            float2 yv = yl[h * 16 + ky];
            float cc = tc[m], ss = ts[m];
            xre += yv.x * cc + yv.y * ss;
            xim += yv.y * cc - yv.x * ss;
            m = (m + kxu) & 255;
        }
        XF[(j * 16 + ky) * 1024 + b * 64 + c] = make_float2(xre, xim);
    }
}

// ---------------- per-layer spectral weight repack (unchanged) ----------------
__global__ __launch_bounds__(256) void k_repack(const float* __restrict__ w1r, const float* __restrict__ w1i,
                                                const float* __restrict__ w2r, const float* __restrict__ w2i,
                                                float2* __restrict__ WPK, int l) {
    int id = blockIdx.x * 256 + threadIdx.x;
    int ky = id & 15;
    int o  = (id >> 4) & 63;
    int i  = (id >> 10) & 63;
    int j  = id >> 16;
    int x  = j & 15;
    const float* wr = (j < 16) ? w1r : w2r;
    const float* wi = (j < 16) ? w1i : w2i;
    int src = ((l * 64 + i) * 64 + o) * 256 + x * 16 + ky;
    int dst = ((j * 16 + ky) * 64 + i) * 64 + o;
    WPK[dst] = make_float2(wr[src], wi[src]);
}

// ---------------- mode mix: W tile staged in LDS ----------------
__global__ __launch_bounds__(256) void k_mix(const float2* __restrict__ XF, const float2* __restrict__ WPK,
                                             float2* __restrict__ YF) {
    __shared__ float2 xs[1024];
    __shared__ float2 wls[4096];
    int s = blockIdx.x;
    int t = threadIdx.x;
    for (int idx = t; idx < 1024; idx += 256) xs[idx] = XF[s * 1024 + idx];
    for (int idx = t; idx < 4096; idx += 256) wls[idx] = WPK[(size_t)s * 4096 + idx];
    __syncthreads();
    int o = t & 63, bg = t >> 6;
    float2 acc[4];
    #pragma unroll
    for (int q = 0; q < 4; q++) acc[q] = make_float2(0.f, 0.f);
    for (int i = 0; i < 64; i++) {
        float2 wv = wls[i * 64 + o];
        #pragma unroll
        for (int q = 0; q < 4; q++) {
            float2 xv = xs[(bg * 4 + q) * 64 + i];
            acc[q].x += xv.x * wv.x - xv.y * wv.y;
            acc[q].y += xv.x * wv.y + xv.y * wv.x;
        }
    }
    #pragma unroll
    for (int q = 0; q < 4; q++) {
        int b = bg * 4 + q;
        YF[(b * 64 + o) * 512 + s] = acc[q];
    }
}

// ---------------- inverse DFT over kx (unchanged) ----------------
__global__ __launch_bounds__(256) void k_inv_h(const float2* __restrict__ YF, float2* __restrict__ Z) {
    __shared__ float2 yl[512];
    __shared__ float tc[256], ts[256];
    int bc = blockIdx.x, t = threadIdx.x;
    {
        float s, c;
        sincosf((float)t * TWO_PI_OVER_256, &s, &c);
        tc[t] = c; ts[t] = s;
    }
    for (int idx = t; idx < 512; idx += 256) yl[idx] = YF[bc * 512 + idx];
    __syncthreads();
    float zr[16], zi[16];
    #pragma unroll
    for (int ky = 0; ky < 16; ky++) { zr[ky] = 0.f; zi[ky] = 0.f; }
    for (int j = 0; j < 32; j++) {
        int kxu = j + ((j < 16) ? 0 : 224);
        int m = (t * kxu) & 255;
        float cc = tc[m], ss = ts[m];
        #pragma unroll
        for (int ky = 0; ky < 16; ky++) {
            float2 yv = yl[j * 16 + ky];
            zr[ky] += yv.x * cc - yv.y * ss;
            zi[ky] += yv.x * ss + yv.y * cc;
        }
    }
    int base = bc * 4096 + t * 16;
    #pragma unroll
    for (int ky = 0; ky < 16; ky++) Z[base + ky] = make_float2(zr[ky], zi[ky]);
}

// ---------------- layer tail: per-nt strips (16 AGPR acc), fast gelu ----------------
//  mode 1 (l<3): + fused forward w-DFT for next layer, + X writeback
//  mode 2 (l=3): + fused proj conv + GELU + spatial sum (no X writeback)
__global__ __launch_bounds__(256) void k_tail(unsigned short* __restrict__ X, const float2* __restrict__ Z,
                                              const unsigned short* __restrict__ WH, const unsigned short* __restrict__ WL,
                                              const float* __restrict__ sbl, const float* __restrict__ bng,
                                              const float* __restrict__ bnb, const float* __restrict__ bnm,
                                              const float* __restrict__ bnv,
                                              const unsigned short* __restrict__ TiH, const unsigned short* __restrict__ TiL,
                                              const unsigned short* __restrict__ TfH, const unsigned short* __restrict__ TfL,
                                              float2* __restrict__ Y, int mode,
                                              const unsigned short* __restrict__ PH, const unsigned short* __restrict__ PL,
                                              const float* __restrict__ pb, float* __restrict__ ACC) {
    __shared__ unsigned short xl[64 * 264];   // 33,792 B
    __shared__ float cbs[64];
    __shared__ float pacc[64];
    __shared__ float pbs[64];
    int b = blockIdx.x >> 8, h = blockIdx.x & 255;
    int t = threadIdx.x;
    unsigned short* Xg = X + (size_t)(b * 64) * 65536 + h * 256;
    // vectorized staging: 16B per lane
    #pragma unroll
    for (int r = 0; r < 8; r++) {
        int idx = r * 256 + t;
        int c = idx >> 5, w8 = idx & 31;
        *(short8*)(&xl[c * 264 + w8 * 8]) = *(const short8*)(Xg + c * 65536 + w8 * 8);
    }
    if (t < 64) {
        float scl = bng[t] * rsqrtf(bnv[t] + 1e-5f);
        cbs[t] = scl * (sbl[t] - bnm[t]) + bnb[t];
        pacc[t] = 0.f;
        pbs[t] = pb[t];
    }
    __syncthreads();

    int wv = t >> 6, ln = t & 63;
    int lx = ln & 15, q = ln >> 4;

    // ---- build Az fragments ONCE in registers (32 VGPRs) ----
    short8 azh[4], azl[4];
    {
        const float2* Zg = Z + (size_t)(b * 64) * 4096 + h * 16;
        #pragma unroll
        for (int mt = 0; mt < 4; mt++) {
            int co = mt * 16 + lx;
            float scl = bng[co] * rsqrtf(bnv[co] + 1e-5f);
            float f2v = scl * (2.0f / 65536.0f);
            float f0 = (q == 0) ? (scl * (1.0f / 65536.0f)) : f2v;
            const float4* zp = (const float4*)(Zg + (size_t)co * 4096 + q * 4);
            float4 z0 = zp[0], z1 = zp[1];
            float v[8];
            v[0] = z0.x * f0;  v[1] = z0.y * f0;
            v[2] = z0.z * f2v; v[3] = z0.w * f2v;
            v[4] = z1.x * f2v; v[5] = z1.y * f2v;
            v[6] = z1.z * f2v; v[7] = z1.w * f2v;
            #pragma unroll
            for (int j = 0; j < 8; j++) {
                unsigned short hv = f2bf(v[j]);
                azh[mt][j] = (short)hv;
                azl[mt][j] = (short)f2bf(v[j] - bf2f(hv));
            }
        }
    }

    // ---- per-nt strips: spectral + skip + epilogue with acc[4] (16 AGPR) ----
    #pragma unroll 1
    for (int nt = 0; nt < 4; nt++) {
        int w = wv * 64 + nt * 16 + lx;
        f32x4 acc[4];
        #pragma unroll
        for (int mt = 0; mt < 4; mt++) acc[mt] = (f32x4){0.f, 0.f, 0.f, 0.f};
        // spectral recon
        {
            short8 tbh = *(const short8*)(TiH + w * 32 + q * 8);
            short8 tbl = *(const short8*)(TiL + w * 32 + q * 8);
            #pragma unroll
            for (int mt = 0; mt < 4; mt++) {
                acc[mt] = mfma16(azh[mt], tbh, acc[mt]);
                acc[mt] = mfma16(azh[mt], tbl, acc[mt]);
                acc[mt] = mfma16(azl[mt], tbh, acc[mt]);
            }
        }
        // skip conv
        #pragma unroll
        for (int ks = 0; ks < 2; ks++) {
            int k0 = ks * 32;
            short8 bfr;
            #pragma unroll
            for (int j = 0; j < 8; j++)
                bfr[j] = (short)xl[(k0 + q * 8 + j) * 264 + w];
            #pragma unroll
            for (int mt = 0; mt < 4; mt++) {
                short8 ah = *(const short8*)(WH + (mt * 16 + lx) * 64 + k0 + q * 8);
                short8 al = *(const short8*)(WL + (mt * 16 + lx) * 64 + k0 + q * 8);
                acc[mt] = mfma16(ah, bfr, acc[mt]);
                acc[mt] = mfma16(al, bfr, acc[mt]);
            }
        }
        // epilogue: xnew = gelu(D + cb) + xold  (own columns only)
        #pragma unroll
        for (int mt = 0; mt < 4; mt++) {
            #pragma unroll
            for (int r = 0; r < 4; r++) {
                int co = mt * 16 + q * 4 + r;
                float y = acc[mt][r] + cbs[co];
                float v = gelu_f(y) + bf2f(xl[co * 264 + w]);
                xl[co * 264 + w] = f2bf(v);
            }
        }
    }
    __syncthreads();

    if (mode == 1) {
        // fused forward w-DFT for next layer
        f32x4 fa0 = {0.f, 0.f, 0.f, 0.f}, fa1 = {0.f, 0.f, 0.f, 0.f};
        for (int ks = 0; ks < 8; ks++) {
            int k0 = ks * 32;
            short8 a = *(const short8*)(&xl[(wv * 16 + lx) * 264 + k0 + q * 8]);
            short8 bh0 = *(const short8*)(TfH + lx * 256 + k0 + q * 8);
            short8 bl0 = *(const short8*)(TfL + lx * 256 + k0 + q * 8);
            short8 bh1 = *(const short8*)(TfH + (16 + lx) * 256 + k0 + q * 8);
            short8 bl1 = *(const short8*)(TfL + (16 + lx) * 256 + k0 + q * 8);
            fa0 = mfma16(a, bh0, fa0); fa0 = mfma16(a, bl0, fa0);
            fa1 = mfma16(a, bh1, fa1); fa1 = mfma16(a, bl1, fa1);
        }
        #pragma unroll
        for (int r = 0; r < 4; r++) {
            int c = wv * 16 + q * 4 + r;
            Y[(b * 64 + c) * 4096 + h * 16 + lx] = make_float2(fa0[r], fa1[r]);
        }
        // vectorized X writeback
        #pragma unroll
        for (int r = 0; r < 8; r++) {
            int idx = r * 256 + t;
            int c = idx >> 5, w8 = idx & 31;
            *(short8*)(Xg + c * 65536 + w8 * 8) = *(const short8*)(&xl[c * 264 + w8 * 8]);
        }
    } else {
        // fused proj conv + GELU + spatial sum (reads NEW xl)
        float psum[4][4];
        #pragma unroll
        for (int mt = 0; mt < 4; mt++)
            #pragma unroll
            for (int r = 0; r < 4; r++) psum[mt][r] = 0.f;
        #pragma unroll 1
        for (int nt = 0; nt < 4; nt++) {
            int w = wv * 64 + nt * 16 + lx;
            f32x4 acc[4];
            #pragma unroll
            for (int mt = 0; mt < 4; mt++) acc[mt] = (f32x4){0.f, 0.f, 0.f, 0.f};
            #pragma unroll
            for (int ks = 0; ks < 2; ks++) {
                int k0 = ks * 32;
                short8 bfr;
                #pragma unroll
                for (int j = 0; j < 8; j++)
                    bfr[j] = (short)xl[(k0 + q * 8 + j) * 264 + w];
                #pragma unroll
                for (int mt = 0; mt < 4; mt++) {
                    short8 ah = *(const short8*)(PH + (mt * 16 + lx) * 64 + k0 + q * 8);
                    short8 al = *(const short8*)(PL + (mt * 16 + lx) * 64 + k0 + q * 8);
                    acc[mt] = mfma16(ah, bfr, acc[mt]);
                    acc[mt] = mfma16(al, bfr, acc[mt]);
                }
            }
            #pragma unroll
            for (int mt = 0; mt < 4; mt++)
                #pragma unroll
                for (int r = 0; r < 4; r++) {
                    int co = mt * 16 + q * 4 + r;
                    psum[mt][r] += gelu_f(acc[mt][r] + pbs[co]);
                }
        }
        #pragma unroll
        for (int mt = 0; mt < 4; mt++) {
            #pragma unroll
            for (int r = 0; r < 4; r++) {
                int co = mt * 16 + q * 4 + r;
                float s = psum[mt][r];
                s += __shfl_xor(s, 1, 64);
                s += __shfl_xor(s, 2, 64);
                s += __shfl_xor(s, 4, 64);
                s += __shfl_xor(s, 8, 64);
                if (lx == 0) atomicAdd(&pacc[co], s);
            }
        }
        __syncthreads();
        if (t < 64) atomicAdd(&ACC[b * 64 + t], pacc[t]);
    }
}

// ---------------- heads ----------------
__global__ __launch_bounds__(128) void k_head(const float* __restrict__ ACC, const float* __restrict__ env,
                                              const float* __restrict__ d1d,
                                              const float* __restrict__ dw1, const float* __restrict__ db1,
                                              const float* __restrict__ dw2, const float* __restrict__ db2,
                                              const float* __restrict__ dw3, const float* __restrict__ db3,
                                              const float* __restrict__ iw1, const float* __restrict__ ib1,
                                              const float* __restrict__ iw2, const float* __restrict__ ib2,
                                              const float* __restrict__ iw3, const float* __restrict__ ib3,
                                              float* __restrict__ out) {
    __shared__ float xc[108];
    __shared__ float h1[128];
    __shared__ float h2[64];
    int b = blockIdx.x, t = threadIdx.x;
    if (t < 64) xc[t] = ACC[b * 64 + t] * (1.0f / 65536.0f);
    else if (t < 104) xc[t] = env[b * 40 + (t - 64)];
    else if (t < 108) xc[t] = d1d[b * 4 + (t - 104)];
    __syncthreads();
    {
        float a = db1[t];
        for (int k = 0; k < 108; k++) a += xc[k] * dw1[t * 108 + k];
        h1[t] = gelu_f(a);
    }
    __syncthreads();
    if (t < 64) {
        float a = db2[t];
        for (int k = 0; k < 128; k++) a += h1[k] * dw2[t * 128 + k];
        h2[t] = gelu_f(a);
    }
    __syncthreads();
    if (t < 8) {
        float a = db3[t];
        for (int k = 0; k < 64; k++) a += h2[k] * dw3[t * 64 + k];
        out[b * 8 + t] = a;
    }
    __syncthreads();
    {
        float a = ib1[t];
        for (int k = 0; k < 108; k++) a += xc[k] * iw1[t * 108 + k];
        h1[t] = gelu_f(a);
    }
    __syncthreads();
    if (t < 64) {
        float a = ib2[t];
        for (int k = 0; k < 128; k++) a += h1[k] * iw2[t * 128 + k];
        h2[t] = gelu_f(a);
    }
    __syncthreads();
    if (t < 4) {
        float a = ib3[t];
        for (int k = 0; k < 64; k++) a += h2[k] * iw3[t * 64 + k];
        out[128 + b * 4 + t] = a;
    }
}

extern "C" void kernel_launch(void* const* d_in, const int* in_sizes, int n_in,
                              void* d_out, int out_size, void* d_ws, size_t ws_size,
                              hipStream_t stream) {
    const float* grid_  = (const float*)d_in[0];
    const float* env    = (const float*)d_in[1];
    const float* d1d    = (const float*)d_in[2];
    const float* lift_w = (const float*)d_in[3];
    const float* lift_b = (const float*)d_in[4];
    const float* w1r    = (const float*)d_in[5];
    const float* w1i    = (const float*)d_in[6];
    const float* w2r    = (const float*)d_in[7];
    const float* w2i    = (const float*)d_in[8];
    const float* skip_w = (const float*)d_in[9];
    const float* skip_b = (const float*)d_in[10];
    const float* bn_g   = (const float*)d_in[11];
    const float* bn_b   = (const float*)d_in[12];
    const float* bn_m   = (const float*)d_in[13];
    const float* bn_v   = (const float*)d_in[14];
    const float* proj_w = (const float*)d_in[15];
    const float* proj_b = (const float*)d_in[16];
    const float* dw1 = (const float*)d_in[17];
    const float* db1 = (const float*)d_in[18];
    const float* dw2 = (const float*)d_in[19];
    const float* db2 = (const float*)d_in[20];
    const float* dw3 = (const float*)d_in[21];
    const float* db3 = (const float*)d_in[22];
    const float* iw1 = (const float*)d_in[23];
    const float* ib1 = (const float*)d_in[24];
    const float* iw2 = (const float*)d_in[25];
    const float* ib2 = (const float*)d_in[26];
    const float* iw3 = (const float*)d_in[27];
    const float* ib3 = (const float*)d_in[28];

    // Workspace layout (total ~193.1 MB)
    char* ws = (char*)d_ws;
    unsigned short* X   = (unsigned short*)(ws);               // 134,217,728
    float2* S   = (float2*)(ws + 134217728);                   //  33,554,432 (Y and Z alias)
    float2* XF  = (float2*)(ws + 167772160);                   //   4,194,304
    float2* YF  = (float2*)(ws + 171966464);                   //   4,194,304
    float2* WPK = (float2*)(ws + 176160768);                   //  16,777,216
    float*  ACC = (float*)(ws + 192937984);                    //       4,096
    unsigned short* TfH = (unsigned short*)(ws + 192942080);   //      16,384
    unsigned short* TfL = (unsigned short*)(ws + 192958464);   //      16,384
    unsigned short* TiH = (unsigned short*)(ws + 192974848);   //      16,384
    unsigned short* TiL = (unsigned short*)(ws + 192991232);   //      16,384
    unsigned short* WH  = (unsigned short*)(ws + 193007616);   //      32,768
    unsigned short* WL  = (unsigned short*)(ws + 193040384);   //      32,768
    unsigned short* PH  = (unsigned short*)(ws + 193073152);   //       8,192
    unsigned short* PL  = (unsigned short*)(ws + 193081344);   //       8,192

    hipMemsetAsync(ACC, 0, 1024 * sizeof(float), stream);
    k_prep<<<144, 256, 0, stream>>>(skip_w, bn_g, bn_v, proj_w, TfH, TfL, TiH, TiL, WH, WL, PH, PL);
    k_lift<<<4096, 256, 0, stream>>>(grid_, lift_w, lift_b, X, TfH, TfL, S);
    for (int l = 0; l < L_; l++) {
        k_repack<<<8192, 256, 0, stream>>>(w1r, w1i, w2r, w2i, WPK, l);
        k_fwd_h<<<1024, 256, 0, stream>>>(S, XF);
        k_mix<<<512, 256, 0, stream>>>(XF, WPK, YF);
        k_inv_h<<<1024, 256, 0, stream>>>(YF, S);
        k_tail<<<4096, 256, 0, stream>>>(X, S, WH + l * 4096, WL + l * 4096,
                                         skip_b + l * 64, bn_g + l * 64, bn_b + l * 64,
                                         bn_m + l * 64, bn_v + l * 64,
                                         TiH, TiL, TfH, TfL, S, (l < 3) ? 1 : 2,
                                         PH, PL, proj_b, ACC);
    }
    k_head<<<16, 128, 0, stream>>>(ACC, env, d1d, dw1, db1, dw2, db2, dw3, db3,
                                   iw1, ib1, iw2, ib2, iw3, ib3, (float*)d_out);
}